// Round 1
// baseline (574.891 us; speedup 1.0000x reference)
//
#include <hip/hip_runtime.h>
#include <stdint.h>

#define NA 200000
#define NB 8
#define NM 64
#define NBIN 65536

// ---- workspace layout (bytes) ----
// scalars: per image 16 u32 slots:
//  [0] num_pos(u32) [1] num_neg(u32) [2] pos_sum(f32) [3] box_sum(f32)
//  [4] k(u32) [5] bin_c(u32) [6] cnt_above1(u32) [7] sum_above1(f32) [8] active(u32)
#define OFF_SCAL   0
#define OFF_L1CNT  512
#define OFF_L1SUM  (512 + 1*2097152)
#define OFF_L2CNT  (512 + 2*2097152)
#define OFF_L2SUM  (512 + 3*2097152)
#define OFF_KEYS   (512 + 4*2097152)
#define ZERO_BYTES OFF_KEYS   // scalars + all 4 histograms

__device__ __forceinline__ unsigned int f2key(float f) {
    unsigned int u = __float_as_uint(f);
    return (u & 0x80000000u) ? ~u : (u | 0x80000000u);
}
__device__ __forceinline__ float key2f(unsigned int k) {
    return (k & 0x80000000u) ? __uint_as_float(k & 0x7fffffffu) : __uint_as_float(~k);
}

// ---------------- K1: IoU max/argmax, pos/neg stats, box loss, neg keys + L1 hist ----------------
__global__ __launch_bounds__(256) void k_main(
    const float* __restrict__ cls, const float* __restrict__ reg,
    const float* __restrict__ anchors, const float* __restrict__ ann,
    unsigned int* __restrict__ scal, unsigned int* __restrict__ l1cnt,
    float* __restrict__ l1sum, unsigned int* __restrict__ keys)
{
    __shared__ float4 sbox[NM];
    __shared__ float2 sav[NM];   // (area_b, valid>0)
    const int b = blockIdx.y;
    const int tid = threadIdx.x;
    if (tid < NM) {
        float4 bb = ((const float4*)ann)[b * NM + tid];
        sbox[tid] = bb;
        float area = (bb.z - bb.x) * (bb.w - bb.y);
        sav[tid] = make_float2(area, (bb.x > 0.0f) ? 1.0f : -1.0f);
    }
    __syncthreads();
    const int i = blockIdx.x * 256 + tid;
    if (i >= NA) return;

    const float4 a = ((const float4*)anchors)[i];
    float best = -3.0e38f;
    int arg = 0;
    {
#pragma clang fp contract(off)
        const float area_a = (a.z - a.x) * (a.w - a.y);
#pragma unroll 4
        for (int m = 0; m < NM; ++m) {
            const float4 bb = sbox[m];
            const float2 av = sav[m];
            float iw = fminf(a.z, bb.z) - fmaxf(a.x, bb.x);
            iw = fmaxf(iw, 0.0f);
            float ih = fminf(a.w, bb.w) - fmaxf(a.y, bb.y);
            ih = fmaxf(ih, 0.0f);
            const float inter = iw * ih;
            const float ua = fmaxf(area_a + av.x - inter, 1e-8f);
            const float iou = inter / ua;           // IEEE division, bit-exact vs ref
            const float v = (av.y > 0.0f) ? iou : -1.0f;
            if (v > best) { best = v; arg = m; }    // strict > : first-occurrence argmax
        }
    }
    const bool pos = (best >= 0.5f);
    const bool neg = (best < 0.3f);
    const float2 cv = ((const float2*)cls)[(size_t)b * NA + i];
    unsigned int* s = scal + b * 16;

    unsigned int key = 0u;   // excluded anchors: key 0 (< any real neg key >= 0x00800000)
    if (neg) {
        const float nl = -cv.y;
        key = f2key(nl);
        atomicAdd(&s[1], 1u);
        atomicAdd(&l1cnt[b * NBIN + (key >> 16)], 1u);
        atomicAdd(&l1sum[b * NBIN + (key >> 16)], nl);
    }
    keys[(size_t)b * NA + i] = key;

    if (pos) {
        atomicAdd(&s[0], 1u);
        atomicAdd((float*)(s + 2), -cv.x);
        const float4 g = sbox[arg];
        const float aw = a.z - a.x, ah = a.w - a.y;
        const float acx = a.x + 0.5f * aw, acy = a.y + 0.5f * ah;
        const float gw = g.z - g.x, gh = g.w - g.y;
        const float gcx = g.x + 0.5f * gw, gcy = g.y + 0.5f * gh;
        const float t0 = ((gcx - acx) / (aw + 1e-14f)) / 0.1f;
        const float t1 = ((gcy - acy) / (ah + 1e-14f)) / 0.1f;
        const float t2 = logf(gw / aw) / 0.2f;
        const float t3 = logf(gh / ah) / 0.2f;
        const float4 r = ((const float4*)reg)[(size_t)b * NA + i];
        const float d0 = fabsf(t0 - r.x);
        const float d1 = fabsf(t1 - r.y);
        const float d2 = fabsf(t2 - r.z);
        const float d3 = fabsf(t3 - r.w);
        const float l0 = (d0 < 1.0f) ? 0.5f * d0 * d0 : d0 - 0.5f;
        const float l1 = (d1 < 1.0f) ? 0.5f * d1 * d1 : d1 - 0.5f;
        const float l2 = (d2 < 1.0f) ? 0.5f * d2 * d2 : d2 - 0.5f;
        const float l3 = (d3 < 1.0f) ? 0.5f * d3 * d3 : d3 - 0.5f;
        atomicAdd((float*)(s + 3), l0 + l1 + l2 + l3);
    }
}

// ---------------- suffix-select helper: find crossing bin in a 65536-bin (count,sum) histogram ----
__device__ __forceinline__ void suffix_select(
    const unsigned int* __restrict__ cnt, const float* __restrict__ sum,
    unsigned int target, unsigned int* out_bin, unsigned int* out_cab, float* out_sab)
{
    __shared__ unsigned int scnt[256];
    __shared__ float ssum[256];
    __shared__ unsigned int ssel[4];
    __shared__ float sselsum[2];
    const int t = threadIdx.x;

    // chunk sums: thread t owns bins [t*256, t*256+256)
    unsigned int cc = 0; float cs = 0.0f;
    const uint4*  cp = (const uint4*)(cnt + t * 256);
    const float4* sp = (const float4*)(sum + t * 256);
#pragma unroll 4
    for (int j = 0; j < 64; ++j) {
        uint4  u = cp[j]; cc += u.x + u.y + u.z + u.w;
        float4 f = sp[j]; cs += f.x + f.y + f.z + f.w;
    }
    scnt[t] = cc; ssum[t] = cs;
    __syncthreads();
    for (int d = 1; d < 256; d <<= 1) {     // inclusive suffix scan
        unsigned int uc = (t + d < 256) ? scnt[t + d] : 0u;
        float fs = (t + d < 256) ? ssum[t + d] : 0.0f;
        __syncthreads();
        scnt[t] += uc; ssum[t] += fs;
        __syncthreads();
    }
    unsigned int nxt = (t < 255) ? scnt[t + 1] : 0u;
    float nxs = (t < 255) ? ssum[t + 1] : 0.0f;
    if (scnt[t] >= target && nxt < target) {
        ssel[0] = (unsigned int)t; ssel[1] = nxt; sselsum[0] = nxs;
    }
    __syncthreads();
    const unsigned int chunk = ssel[0];
    const unsigned int base  = ssel[1];
    const float bases = sselsum[0];

    // bin level within chunk
    unsigned int bc = cnt[chunk * 256 + t];
    float bs = sum[chunk * 256 + t];
    __syncthreads();
    scnt[t] = bc; ssum[t] = bs;
    __syncthreads();
    for (int d = 1; d < 256; d <<= 1) {
        unsigned int uc = (t + d < 256) ? scnt[t + d] : 0u;
        float fs = (t + d < 256) ? ssum[t + d] : 0.0f;
        __syncthreads();
        scnt[t] += uc; ssum[t] += fs;
        __syncthreads();
    }
    nxt = (t < 255) ? scnt[t + 1] : 0u;
    nxs = (t < 255) ? ssum[t + 1] : 0.0f;
    if (base + scnt[t] >= target && base + nxt < target) {
        ssel[2] = chunk * 256 + (unsigned int)t;
        ssel[3] = base + nxt;
        sselsum[1] = bases + nxs;
    }
    __syncthreads();
    *out_bin = ssel[2]; *out_cab = ssel[3]; *out_sab = sselsum[1];
}

// ---------------- K2: per-image L1 bin selection ----------------
__global__ __launch_bounds__(256) void k_sel1(
    unsigned int* __restrict__ scal, const unsigned int* __restrict__ l1cnt,
    const float* __restrict__ l1sum)
{
    const int b = blockIdx.x;
    unsigned int* s = scal + b * 16;
    const unsigned int np = s[0], nn = s[1];
    unsigned int k = 0;
    if (np > 0) { unsigned int kp = np * 3u; k = (kp < nn) ? kp : nn; }
    if (threadIdx.x == 0) { s[4] = k; s[8] = (k > 0) ? 1u : 0u; }
    if (k == 0) return;   // block-uniform
    unsigned int bin, cab; float sab;
    suffix_select(l1cnt + (size_t)b * NBIN, l1sum + (size_t)b * NBIN, k, &bin, &cab, &sab);
    if (threadIdx.x == 0) { s[5] = bin; s[6] = cab; ((float*)s)[7] = sab; }
}

// ---------------- K3: L2 histogram of the selected L1 bin ----------------
__global__ __launch_bounds__(256) void k_hist2(
    const unsigned int* __restrict__ keys, const unsigned int* __restrict__ scal,
    unsigned int* __restrict__ l2cnt, float* __restrict__ l2sum)
{
    const int b = blockIdx.y;
    const unsigned int* s = scal + b * 16;
    if (s[8] == 0u) return;
    const unsigned int c = s[5];
    const int i = blockIdx.x * 256 + threadIdx.x;
    if (i >= NA) return;
    const unsigned int key = keys[(size_t)b * NA + i];
    if ((key >> 16) == c) {
        atomicAdd(&l2cnt[(size_t)b * NBIN + (key & 0xffffu)], 1u);
        atomicAdd(&l2sum[(size_t)b * NBIN + (key & 0xffffu)], key2f(key));
    }
}

// ---------------- K4: L2 selection + finalize losses ----------------
__global__ __launch_bounds__(256) void k_final(
    const unsigned int* __restrict__ scal, const unsigned int* __restrict__ l2cnt,
    const float* __restrict__ l2sum, float* __restrict__ out)
{
    const int b = blockIdx.x;
    const unsigned int* s = scal + b * 16;
    const float* fsc = (const float*)s;
    const unsigned int np = s[0];
    const unsigned int k = s[4];
    float sum_top = 0.0f;
    if (k > 0) {   // block-uniform
        const unsigned int target2 = k - s[6];
        unsigned int bin2, cab2; float sab2;
        suffix_select(l2cnt + (size_t)b * NBIN, l2sum + (size_t)b * NBIN, target2, &bin2, &cab2, &sab2);
        const unsigned int keyv = (s[5] << 16) | bin2;
        const float v = key2f(keyv);
        const unsigned int rem = target2 - cab2;      // ties at threshold: exact count
        sum_top = fsc[7] + sab2 + (float)rem * v;
    }
    if (threadIdx.x == 0) {
        float cls_loss = 0.0f, box_loss = 0.0f;
        if (np > 0) {
            const float pos_mean = fsc[2] / (float)np;
            const float neg_mean = sum_top / (float)((k > 0) ? k : 1u);
            cls_loss = pos_mean + neg_mean;
            box_loss = fsc[3] / (float)(4u * np);
        }
        out[b] = cls_loss;
        out[NB + b] = box_loss;
    }
}

extern "C" void kernel_launch(void* const* d_in, const int* in_sizes, int n_in,
                              void* d_out, int out_size, void* d_ws, size_t ws_size,
                              hipStream_t stream) {
    const float* cls     = (const float*)d_in[0];   // (B, A, 2)
    const float* reg     = (const float*)d_in[1];   // (B, A, 4)
    const float* anchors = (const float*)d_in[2];   // (1, A, 4)
    const float* ann     = (const float*)d_in[3];   // (B, M, 4)
    uint8_t* ws = (uint8_t*)d_ws;
    unsigned int* scal  = (unsigned int*)(ws + OFF_SCAL);
    unsigned int* l1cnt = (unsigned int*)(ws + OFF_L1CNT);
    float*        l1sum = (float*)(ws + OFF_L1SUM);
    unsigned int* l2cnt = (unsigned int*)(ws + OFF_L2CNT);
    float*        l2sum = (float*)(ws + OFF_L2SUM);
    unsigned int* keys  = (unsigned int*)(ws + OFF_KEYS);

    (void)in_sizes; (void)n_in; (void)out_size; (void)ws_size;

    hipMemsetAsync(d_ws, 0, ZERO_BYTES, stream);
    dim3 grid((NA + 255) / 256, NB);
    k_main<<<grid, 256, 0, stream>>>(cls, reg, anchors, ann, scal, l1cnt, l1sum, keys);
    k_sel1<<<dim3(NB), 256, 0, stream>>>(scal, l1cnt, l1sum);
    k_hist2<<<grid, 256, 0, stream>>>(keys, scal, l2cnt, l2sum);
    k_final<<<dim3(NB), 256, 0, stream>>>(scal, l2cnt, l2sum, (float*)d_out);
}

// Round 2
// 302.806 us; speedup vs baseline: 1.8985x; 1.8985x over previous
//
#include <hip/hip_runtime.h>
#include <stdint.h>

#define NA 200000
#define NB 8
#define NM 64

// ---- workspace layout (bytes) ----
// per-image scalar slots (16 u32):
//  [0] num_pos [1] num_neg [2] pos_sum(f32) [3] box_sum(f32)
//  [4] k [5] c1 [6] cnt_above1 [7] sum_above1(f32) [8] active
//  [9] c2 [10] cnt_above2 [11] sum_above2(f32)
#define OFF_SCAL   0
#define OFF_L1CNT  512                       // 8*256*4   = 8192
#define OFF_L1SUM  (OFF_L1CNT + 8192)        // 8192
#define OFF_L2CNT  (OFF_L1SUM + 8192)        // 8*4096*4  = 131072
#define OFF_L2SUM  (OFF_L2CNT + 131072)
#define OFF_L3CNT  (OFF_L2SUM + 131072)
#define OFF_L3SUM  (OFF_L3CNT + 131072)
#define OFF_KEYS   (OFF_L3SUM + 131072)      // 8*200000*4 = 6.4 MB
#define ZERO_BYTES OFF_KEYS                  // 541184 B: scalars + all histograms

__device__ __forceinline__ unsigned int f2key(float f) {
    unsigned int u = __float_as_uint(f);
    return (u & 0x80000000u) ? ~u : (u | 0x80000000u);
}
__device__ __forceinline__ float key2f(unsigned int k) {
    return (k & 0x80000000u) ? __uint_as_float(k & 0x7fffffffu) : __uint_as_float(~k);
}

// ---------------- K1: IoU max/argmax, stats, box loss, neg keys + L1(8-bit) hist ----------------
__global__ __launch_bounds__(256) void k_main(
    const float* __restrict__ cls, const float* __restrict__ reg,
    const float* __restrict__ anchors, const float* __restrict__ ann,
    unsigned int* __restrict__ scal, unsigned int* __restrict__ l1cnt,
    float* __restrict__ l1sum, unsigned int* __restrict__ keys)
{
    __shared__ float4 sbox[NM];
    __shared__ float2 sav[NM];          // (area_b, valid>0)
    __shared__ unsigned int h_cnt[256];
    __shared__ float h_sum[256];
    __shared__ unsigned int s_np, s_nn;
    __shared__ float s_ps, s_bs;

    const int b = blockIdx.y;
    const int tid = threadIdx.x;
    if (tid < NM) {
        float4 bb = ((const float4*)ann)[b * NM + tid];
        sbox[tid] = bb;
        float area = (bb.z - bb.x) * (bb.w - bb.y);
        sav[tid] = make_float2(area, (bb.x > 0.0f) ? 1.0f : -1.0f);
    }
    h_cnt[tid] = 0u; h_sum[tid] = 0.0f;
    if (tid == 0) { s_np = 0u; s_nn = 0u; s_ps = 0.0f; s_bs = 0.0f; }
    __syncthreads();

    const int i = blockIdx.x * 256 + tid;
    const bool act = (i < NA);
    bool pos = false, neg = false;
    float posv = 0.0f, boxv = 0.0f;

    if (act) {
        const float4 a = ((const float4*)anchors)[i];
        float best = -3.0e38f;
        int arg = 0;
        {
#pragma clang fp contract(off)
            const float area_a = (a.z - a.x) * (a.w - a.y);
#pragma unroll 4
            for (int m = 0; m < NM; ++m) {
                const float4 bb = sbox[m];
                const float2 av = sav[m];
                float iw = fminf(a.z, bb.z) - fmaxf(a.x, bb.x);
                iw = fmaxf(iw, 0.0f);
                float ih = fminf(a.w, bb.w) - fmaxf(a.y, bb.y);
                ih = fmaxf(ih, 0.0f);
                const float inter = iw * ih;
                const float ua = fmaxf(area_a + av.x - inter, 1e-8f);
                const float iou = inter / ua;        // IEEE division, bit-exact vs ref
                const float v = (av.y > 0.0f) ? iou : -1.0f;
                if (v > best) { best = v; arg = m; } // strict > : first-occurrence argmax
            }
        }
        pos = (best >= 0.5f);
        neg = (best < 0.3f);
        const float2 cv = ((const float2*)cls)[(size_t)b * NA + i];

        unsigned int key = 0u;  // excluded: key 0 (< any real key >= 0x00800000)
        if (neg) {
            const float nl = -cv.y;
            key = f2key(nl);
            atomicAdd(&h_cnt[key >> 24], 1u);
            atomicAdd(&h_sum[key >> 24], nl);
        }
        keys[(size_t)b * NA + i] = key;

        if (pos) {
            posv = -cv.x;
            const float4 g = sbox[arg];
            const float aw = a.z - a.x, ah = a.w - a.y;
            const float acx = a.x + 0.5f * aw, acy = a.y + 0.5f * ah;
            const float gw = g.z - g.x, gh = g.w - g.y;
            const float gcx = g.x + 0.5f * gw, gcy = g.y + 0.5f * gh;
            const float t0 = ((gcx - acx) / (aw + 1e-14f)) / 0.1f;
            const float t1 = ((gcy - acy) / (ah + 1e-14f)) / 0.1f;
            const float t2 = logf(gw / aw) / 0.2f;
            const float t3 = logf(gh / ah) / 0.2f;
            const float4 r = ((const float4*)reg)[(size_t)b * NA + i];
            const float d0 = fabsf(t0 - r.x);
            const float d1 = fabsf(t1 - r.y);
            const float d2 = fabsf(t2 - r.z);
            const float d3 = fabsf(t3 - r.w);
            const float l0 = (d0 < 1.0f) ? 0.5f * d0 * d0 : d0 - 0.5f;
            const float l1 = (d1 < 1.0f) ? 0.5f * d1 * d1 : d1 - 0.5f;
            const float l2 = (d2 < 1.0f) ? 0.5f * d2 * d2 : d2 - 0.5f;
            const float l3 = (d3 < 1.0f) ? 0.5f * d3 * d3 : d3 - 0.5f;
            boxv = l0 + l1 + l2 + l3;
        }
    }

    // wave-level aggregation -> block LDS -> one flush per block
    const unsigned long long pb = __ballot(pos);
    const unsigned long long nb = __ballot(neg);
    if (pb) {
        for (int off = 32; off; off >>= 1) {
            posv += __shfl_xor(posv, off);
            boxv += __shfl_xor(boxv, off);
        }
    }
    if ((tid & 63) == 0) {
        if (nb) atomicAdd(&s_nn, (unsigned int)__popcll(nb));
        if (pb) {
            atomicAdd(&s_np, (unsigned int)__popcll(pb));
            atomicAdd(&s_ps, posv);
            atomicAdd(&s_bs, boxv);
        }
    }
    __syncthreads();

    unsigned int* sg = scal + b * 16;
    if (tid == 0) {
        if (s_nn) atomicAdd(&sg[1], s_nn);
        if (s_np) {
            atomicAdd(&sg[0], s_np);
            atomicAdd((float*)(sg + 2), s_ps);
            atomicAdd((float*)(sg + 3), s_bs);
        }
    }
    if (h_cnt[tid]) {
        atomicAdd(&l1cnt[b * 256 + tid], h_cnt[tid]);
        atomicAdd(&l1sum[b * 256 + tid], h_sum[tid]);
    }
}

// ---------------- K2: level-1 select over 256 bins ----------------
__global__ __launch_bounds__(256) void k_sel1(
    unsigned int* __restrict__ scal, const unsigned int* __restrict__ l1cnt,
    const float* __restrict__ l1sum)
{
    const int b = blockIdx.x;
    const int t = threadIdx.x;
    unsigned int* s = scal + b * 16;
    const unsigned int np = s[0], nn = s[1];
    unsigned int k = 0;
    if (np > 0) { unsigned int kp = np * 3u; k = (kp < nn) ? kp : nn; }
    if (t == 0) { s[4] = k; s[8] = (k > 0) ? 1u : 0u; }
    if (k == 0) return;   // uniform

    __shared__ unsigned int sc[256];
    __shared__ float ss[256];
    sc[t] = l1cnt[b * 256 + t];
    ss[t] = l1sum[b * 256 + t];
    __syncthreads();
    for (int d = 1; d < 256; d <<= 1) {   // inclusive suffix scan
        unsigned int uc = (t + d < 256) ? sc[t + d] : 0u;
        float fs = (t + d < 256) ? ss[t + d] : 0.0f;
        __syncthreads();
        sc[t] += uc; ss[t] += fs;
        __syncthreads();
    }
    const unsigned int nxt = (t < 255) ? sc[t + 1] : 0u;
    const float nxs = (t < 255) ? ss[t + 1] : 0.0f;
    if (sc[t] >= k && nxt < k) {
        s[5] = (unsigned int)t; s[6] = nxt; ((float*)s)[7] = nxs;
    }
}

// ---------------- shared helper: exact select over a 4096-bin histogram ----------------
// r[0]=bin, r[1]=count strictly above bin (within this histogram), r[2]=sum above (f32 bits)
__device__ __forceinline__ void sel4096(
    const unsigned int* __restrict__ cnt, const float* __restrict__ sum,
    unsigned int target, unsigned int* r)
{
    __shared__ unsigned int sc[256];
    __shared__ float ss[256];
    const int t = threadIdx.x;
    unsigned int cb[16]; float sb[16];
    unsigned int cc = 0; float cs = 0.0f;
#pragma unroll
    for (int j = 0; j < 16; ++j) {
        cb[j] = cnt[t * 16 + j]; sb[j] = sum[t * 16 + j];
        cc += cb[j]; cs += sb[j];
    }
    sc[t] = cc; ss[t] = cs;
    __syncthreads();
    for (int d = 1; d < 256; d <<= 1) {
        unsigned int uc = (t + d < 256) ? sc[t + d] : 0u;
        float fs = (t + d < 256) ? ss[t + d] : 0.0f;
        __syncthreads();
        sc[t] += uc; ss[t] += fs;
        __syncthreads();
    }
    unsigned int run = (t < 255) ? sc[t + 1] : 0u;
    float runs = (t < 255) ? ss[t + 1] : 0.0f;
#pragma unroll
    for (int j = 15; j >= 0; --j) {
        const unsigned int prev = run; const float prevs = runs;
        run += cb[j]; runs += sb[j];
        if (run >= target && prev < target) {
            r[0] = (unsigned int)(t * 16 + j); r[1] = prev; ((float*)r)[2] = prevs;
        }
    }
    __syncthreads();
}

// ---------------- K3: level-2 histogram (12 bits) of keys in selected L1 bin ----------------
__global__ __launch_bounds__(256) void k_hist2(
    const unsigned int* __restrict__ keys, const unsigned int* __restrict__ scal,
    unsigned int* __restrict__ l2cnt, float* __restrict__ l2sum)
{
    const int b = blockIdx.y;
    const unsigned int* s = scal + b * 16;
    if (s[8] == 0u) return;
    const unsigned int c1 = s[5];
    __shared__ unsigned int hc[4096];
    __shared__ float hs[4096];
    const int tid = threadIdx.x;
    for (int j = tid; j < 4096; j += 256) { hc[j] = 0u; hs[j] = 0.0f; }
    __syncthreads();
    const int i = blockIdx.x * 256 + tid;
    if (i < NA) {
        const unsigned int key = keys[(size_t)b * NA + i];
        if (key && (key >> 24) == c1) {
            const unsigned int bin = (key >> 12) & 0xfffu;
            atomicAdd(&hc[bin], 1u);
            atomicAdd(&hs[bin], key2f(key));
        }
    }
    __syncthreads();
    for (int j = tid; j < 4096; j += 256) {
        if (hc[j]) {
            atomicAdd(&l2cnt[b * 4096 + j], hc[j]);
            atomicAdd(&l2sum[b * 4096 + j], hs[j]);
        }
    }
}

// ---------------- K4: level-2 select ----------------
__global__ __launch_bounds__(256) void k_sel2(
    unsigned int* __restrict__ scal, const unsigned int* __restrict__ l2cnt,
    const float* __restrict__ l2sum)
{
    const int b = blockIdx.x;
    unsigned int* s = scal + b * 16;
    if (s[8] == 0u) return;
    __shared__ unsigned int r[3];
    sel4096(l2cnt + b * 4096, l2sum + b * 4096, s[4] - s[6], r);
    if (threadIdx.x == 0) {
        s[9] = r[0];
        s[10] = s[6] + r[1];
        ((float*)s)[11] = ((float*)s)[7] + ((float*)r)[2];
    }
}

// ---------------- K5: level-3 histogram (low 12 bits) ----------------
__global__ __launch_bounds__(256) void k_hist3(
    const unsigned int* __restrict__ keys, const unsigned int* __restrict__ scal,
    unsigned int* __restrict__ l3cnt, float* __restrict__ l3sum)
{
    const int b = blockIdx.y;
    const unsigned int* s = scal + b * 16;
    if (s[8] == 0u) return;
    const unsigned int top20 = (s[5] << 12) | s[9];
    __shared__ unsigned int hc[4096];
    __shared__ float hs[4096];
    const int tid = threadIdx.x;
    for (int j = tid; j < 4096; j += 256) { hc[j] = 0u; hs[j] = 0.0f; }
    __syncthreads();
    const int i = blockIdx.x * 256 + tid;
    if (i < NA) {
        const unsigned int key = keys[(size_t)b * NA + i];
        if (key && (key >> 12) == top20) {
            const unsigned int bin = key & 0xfffu;
            atomicAdd(&hc[bin], 1u);
            atomicAdd(&hs[bin], key2f(key));
        }
    }
    __syncthreads();
    for (int j = tid; j < 4096; j += 256) {
        if (hc[j]) {
            atomicAdd(&l3cnt[b * 4096 + j], hc[j]);
            atomicAdd(&l3sum[b * 4096 + j], hs[j]);
        }
    }
}

// ---------------- K6: level-3 select + finalize ----------------
__global__ __launch_bounds__(256) void k_final(
    const unsigned int* __restrict__ scal, const unsigned int* __restrict__ l3cnt,
    const float* __restrict__ l3sum, float* __restrict__ out)
{
    const int b = blockIdx.x;
    const unsigned int* s = scal + b * 16;
    const float* fsc = (const float*)s;
    __shared__ unsigned int r[3];
    __shared__ float s_top;
    const unsigned int np = s[0], k = s[4];
    if (threadIdx.x == 0) s_top = 0.0f;
    __syncthreads();
    if (s[8]) {   // uniform
        const unsigned int target3 = k - s[10];
        sel4096(l3cnt + b * 4096, l3sum + b * 4096, target3, r);
        if (threadIdx.x == 0) {
            const unsigned int keyv = (s[5] << 24) | (s[9] << 12) | r[0];
            const float v = key2f(keyv);
            const unsigned int rem = target3 - r[1];   // exact tie handling
            s_top = fsc[11] + ((float*)r)[2] + (float)rem * v;
        }
    }
    __syncthreads();
    if (threadIdx.x == 0) {
        float cls_loss = 0.0f, box_loss = 0.0f;
        if (np > 0) {
            const float pos_mean = fsc[2] / (float)np;
            const float neg_mean = s_top / (float)((k > 0) ? k : 1u);
            cls_loss = pos_mean + neg_mean;
            box_loss = fsc[3] / (float)(4u * np);
        }
        out[b] = cls_loss;
        out[NB + b] = box_loss;
    }
}

extern "C" void kernel_launch(void* const* d_in, const int* in_sizes, int n_in,
                              void* d_out, int out_size, void* d_ws, size_t ws_size,
                              hipStream_t stream) {
    const float* cls     = (const float*)d_in[0];   // (B, A, 2)
    const float* reg     = (const float*)d_in[1];   // (B, A, 4)
    const float* anchors = (const float*)d_in[2];   // (1, A, 4)
    const float* ann     = (const float*)d_in[3];   // (B, M, 4)
    uint8_t* ws = (uint8_t*)d_ws;
    unsigned int* scal  = (unsigned int*)(ws + OFF_SCAL);
    unsigned int* l1cnt = (unsigned int*)(ws + OFF_L1CNT);
    float*        l1sum = (float*)(ws + OFF_L1SUM);
    unsigned int* l2cnt = (unsigned int*)(ws + OFF_L2CNT);
    float*        l2sum = (float*)(ws + OFF_L2SUM);
    unsigned int* l3cnt = (unsigned int*)(ws + OFF_L3CNT);
    float*        l3sum = (float*)(ws + OFF_L3SUM);
    unsigned int* keys  = (unsigned int*)(ws + OFF_KEYS);

    (void)in_sizes; (void)n_in; (void)out_size; (void)ws_size;

    hipMemsetAsync(d_ws, 0, ZERO_BYTES, stream);
    dim3 grid((NA + 255) / 256, NB);
    k_main <<<grid, 256, 0, stream>>>(cls, reg, anchors, ann, scal, l1cnt, l1sum, keys);
    k_sel1 <<<dim3(NB), 256, 0, stream>>>(scal, l1cnt, l1sum);
    k_hist2<<<grid, 256, 0, stream>>>(keys, scal, l2cnt, l2sum);
    k_sel2 <<<dim3(NB), 256, 0, stream>>>(scal, l2cnt, l2sum);
    k_hist3<<<grid, 256, 0, stream>>>(keys, scal, l3cnt, l3sum);
    k_final<<<dim3(NB), 256, 0, stream>>>(scal, l3cnt, l3sum, (float*)d_out);
}